// Round 10
// baseline (258.721 us; speedup 1.0000x reference)
//
#include <hip/hip_runtime.h>
#include <hip/hip_bf16.h>
#include <math.h>

typedef __hip_bfloat16 bf16;
typedef __attribute__((ext_vector_type(8))) short short8;
typedef __attribute__((ext_vector_type(4))) float f32x4;

#define C_DIM 1024
#define NHEAD 16
#define HS 64

__device__ __forceinline__ float bf2f(bf16 x) { return __bfloat162float(x); }
__device__ __forceinline__ short bfbits(float x) {
    bf16 h = __float2bfloat16(x);
    return *reinterpret_cast<short*>(&h);
}

// Async global->LDS, 16B per lane. LDS dest is wave-uniform base + lane*16.
__device__ __forceinline__ void gl16(const void* g, void* l) {
    __builtin_amdgcn_global_load_lds(
        (const __attribute__((address_space(1))) unsigned int*)g,
        (__attribute__((address_space(3))) unsigned int*)l, 16, 0, 0);
}

// Split 8 consecutive floats into bf16 hi + bf16 lo (residual) short8s.
__device__ __forceinline__ void split8(const float* p, short8& h, short8& l) {
    float4 f0 = reinterpret_cast<const float4*>(p)[0];
    float4 f1 = reinterpret_cast<const float4*>(p)[1];
    float vals[8] = {f0.x, f0.y, f0.z, f0.w, f1.x, f1.y, f1.z, f1.w};
#pragma unroll
    for (int j = 0; j < 8; ++j) {
        bf16 hb = __float2bfloat16(vals[j]);
        float r = vals[j] - __bfloat162float(hb);
        h[j] = *reinterpret_cast<short*>(&hb);
        bf16 lb = __float2bfloat16(r);
        l[j] = *reinterpret_cast<short*>(&lb);
    }
}

// Swizzled-LDS fragment read: [rows][64] bf16 tile, 16B chunk slot = ch ^ (row&7).
__device__ __forceinline__ short8* tchunk(bf16* tile, int row, int ch) {
    return reinterpret_cast<short8*>(tile + row * 64 + (((ch) ^ (row & 7)) << 3));
}

// ---------------------------------------------------------------------------
// Pre-split x,Wq,Wk,Wv -> bf16 hi/lo, stored PRE-SWIZZLED (chunk bits [5:3] of
// the element index XOR'd with row&7, row = idx>>10). Grid 2560 x 256.
// ---------------------------------------------------------------------------
__global__ __launch_bounds__(256) void presplit_all_kernel(
    const float* __restrict__ x, const float* __restrict__ Wq,
    const float* __restrict__ Wk, const float* __restrict__ Wv,
    bf16* __restrict__ xh, bf16* __restrict__ xl,
    bf16* __restrict__ wqh, bf16* __restrict__ wql,
    bf16* __restrict__ wkh, bf16* __restrict__ wkl,
    bf16* __restrict__ wvh, bf16* __restrict__ wvl)
{
    int blk = blockIdx.x;
    const float* src; bf16 *dh, *dl; long off;
    if (blk < 1024)      { src = x;  dh = xh;  dl = xl;  off = (long)blk * 2048; }
    else if (blk < 1536) { src = Wq; dh = wqh; dl = wql; off = (long)(blk - 1024) * 2048; }
    else if (blk < 2048) { src = Wk; dh = wkh; dl = wkl; off = (long)(blk - 1536) * 2048; }
    else                 { src = Wv; dh = wvh; dl = wvl; off = (long)(blk - 2048) * 2048; }
    long p = off + threadIdx.x * 8;
    int j = (int)(((p >> 3) ^ (p >> 10)) & 7);
    long dp = (p & ~56l) | ((long)j << 3);
    short8 h8, l8;
    split8(&src[p], h8, l8);
    *reinterpret_cast<short8*>(&dh[dp]) = h8;
    *reinterpret_cast<short8*>(&dl[dp]) = l8;
}

// Pre-split Wc (pre-swizzled). Runs after setfeat (dest overlays Wm4).
__global__ __launch_bounds__(256) void presplit_wc_kernel(
    const float* __restrict__ Wc, bf16* __restrict__ wch, bf16* __restrict__ wcl)
{
    long p = (long)blockIdx.x * 2048 + threadIdx.x * 8;
    int j = (int)(((p >> 3) ^ (p >> 10)) & 7);
    long dp = (p & ~56l) | ((long)j << 3);
    short8 h8, l8;
    split8(&Wc[p], h8, l8);
    *reinterpret_cast<short8*>(&wch[dp]) = h8;
    *reinterpret_cast<short8*>(&wcl[dp]) = l8;
}

// ---------------------------------------------------------------------------
// Pre-split Wkmap/Wvmap -> Wm4[d][part][row][e] bf16 (part 0=Kh 1=Kl 2=Vh 3=Vl),
// pre-swizzled within each 64-elem row. Grid 64 (one block per d).
// ---------------------------------------------------------------------------
__global__ __launch_bounds__(256) void presplit_wmap_kernel(
    const float* __restrict__ WK, const float* __restrict__ WV, bf16* __restrict__ Wm4)
{
    int d = blockIdx.x;
    int row = threadIdx.x >> 2, e0 = (threadIdx.x & 3) * 16;
    int sw0 = (((e0 >> 3) + 0) ^ (row & 7)) & 7;
    int sw1 = (((e0 >> 3) + 1) ^ (row & 7)) & 7;
    const float* pk = &WK[(long)row * 4096 + d * 64 + e0];
    const float* pv = &WV[(long)row * 4096 + d * 64 + e0];
    long bKh = ((long)(d * 4 + 0) * 64 + row) * 64;
    long bKl = ((long)(d * 4 + 1) * 64 + row) * 64;
    long bVh = ((long)(d * 4 + 2) * 64 + row) * 64;
    long bVl = ((long)(d * 4 + 3) * 64 + row) * 64;
    short8 h8, l8;
    split8(pk, h8, l8);     *(short8*)&Wm4[bKh + sw0*8] = h8; *(short8*)&Wm4[bKl + sw0*8] = l8;
    split8(pk + 8, h8, l8); *(short8*)&Wm4[bKh + sw1*8] = h8; *(short8*)&Wm4[bKl + sw1*8] = l8;
    split8(pv, h8, l8);     *(short8*)&Wm4[bVh + sw0*8] = h8; *(short8*)&Wm4[bVl + sw0*8] = l8;
    split8(pv + 8, h8, l8); *(short8*)&Wm4[bVh + sw1*8] = h8; *(short8*)&Wm4[bVl + sw1*8] = l8;
}

// ---------------------------------------------------------------------------
// Fused QKV GEMM; staging via global_load_lds from pre-swizzled operands.
// proj==1 (k): epilogue transposes per-wave 64x64 quadrant via LDS and writes
// kTg[pair][d][s] (pair = tblk*16 + h) instead of the normal k layout.
// ---------------------------------------------------------------------------
__global__ __launch_bounds__(256) void qkv_kernel(
    const bf16* __restrict__ xh, const bf16* __restrict__ xl,
    const bf16* __restrict__ wqh, const bf16* __restrict__ wql,
    const bf16* __restrict__ wkh, const bf16* __restrict__ wkl,
    const bf16* __restrict__ wvh, const bf16* __restrict__ wvl,
    float* __restrict__ qkv, float* __restrict__ kTg)
{
    __shared__ bf16 lds[32768];   // Ah 0 | Al 8192 | Bh 16384 | Bl 24576 (elems)
    const int tid = threadIdx.x;
    const int lane = tid & 63, wid = tid >> 6;
    const int wr = wid >> 1, wc = wid & 1;
    const int proj = blockIdx.x >> 3;
    const int n0 = (blockIdx.x & 7) * 128;
    const int m0 = blockIdx.y * 128;
    const bf16* Bhp = proj == 0 ? wqh : (proj == 1 ? wkh : wvh);
    const bf16* Blp = proj == 0 ? wql : (proj == 1 ? wkl : wvl);
    float* C = qkv + (long)proj * 2097152;
    char* lb = reinterpret_cast<char*>(lds);

    f32x4 acc[4][4] = {};
    for (int kt = 0; kt < 16; ++kt) {
        const int k0 = kt << 6;
#pragma unroll
        for (int i = 0; i < 4; ++i) {
            int cc = tid + i * 256;             // 1024 chunks per tile
            int row = cc >> 3, j = cc & 7;
            long soA = (long)(m0 + row) * 1024 + k0 + j * 8;
            long soB = (long)(n0 + row) * 1024 + k0 + j * 8;
            gl16(&xh[soA],  lb + cc * 16);
            gl16(&xl[soA],  lb + 16384 + cc * 16);
            gl16(&Bhp[soB], lb + 32768 + cc * 16);
            gl16(&Blp[soB], lb + 49152 + cc * 16);
        }
        __syncthreads();
#pragma unroll
        for (int kk = 0; kk < 2; ++kk) {
            short8 afh[4], afl[4], bfh[4], bfl[4];
#pragma unroll
            for (int t = 0; t < 4; ++t) {
                int ra = wr * 64 + t * 16 + (lane & 15);
                int rb = wc * 64 + t * 16 + (lane & 15);
                int ch = kk * 4 + (lane >> 4);
                afh[t] = *tchunk(lds, ra, ch);
                afl[t] = *tchunk(lds + 8192, ra, ch);
                bfh[t] = *tchunk(lds + 16384, rb, ch);
                bfl[t] = *tchunk(lds + 24576, rb, ch);
            }
#pragma unroll
            for (int tm = 0; tm < 4; ++tm)
#pragma unroll
                for (int tn = 0; tn < 4; ++tn) {
                    acc[tm][tn] = __builtin_amdgcn_mfma_f32_16x16x32_bf16(
                        afh[tm], bfh[tn], acc[tm][tn], 0, 0, 0);
                    acc[tm][tn] = __builtin_amdgcn_mfma_f32_16x16x32_bf16(
                        afh[tm], bfl[tn], acc[tm][tn], 0, 0, 0);
                    acc[tm][tn] = __builtin_amdgcn_mfma_f32_16x16x32_bf16(
                        afl[tm], bfh[tn], acc[tm][tn], 0, 0, 0);
                }
        }
        __syncthreads();
    }
    if (proj == 1) {
        // per-wave 64x64 transpose via its own 16KB LDS quarter (XOR-swizzled)
        float* lf = reinterpret_cast<float*>(lds) + wid * 4096;
#pragma unroll
        for (int tm = 0; tm < 4; ++tm)
#pragma unroll
            for (int tn = 0; tn < 4; ++tn)
#pragma unroll
                for (int r = 0; r < 4; ++r) {
                    int s = tm * 16 + (lane >> 4) * 4 + r;
                    int dd = tn * 16 + (lane & 15);
                    float v = acc[tm][tn][r];
                    v = v > 0.f ? v + 1.f : __expf(v);
                    lf[dd * 64 + (s ^ dd)] = v;
                }
        asm volatile("s_waitcnt lgkmcnt(0)" ::: "memory");
        __builtin_amdgcn_sched_barrier(0);
        int pair = (blockIdx.y * 2 + wr) * 16 + ((blockIdx.x & 7) * 2 + wc);
        long pb = (long)pair * 4096;
        int s0 = (lane & 15) * 4;
#pragma unroll
        for (int ii = 0; ii < 16; ++ii) {
            int dd = (lane >> 4) * 16 + ii;
            float4 o;
            o.x = lf[dd * 64 + ((s0 + 0) ^ dd)];
            o.y = lf[dd * 64 + ((s0 + 1) ^ dd)];
            o.z = lf[dd * 64 + ((s0 + 2) ^ dd)];
            o.w = lf[dd * 64 + ((s0 + 3) ^ dd)];
            *reinterpret_cast<float4*>(&kTg[pb + (long)dd * 64 + s0]) = o;
        }
    } else {
#pragma unroll
        for (int tm = 0; tm < 4; ++tm)
#pragma unroll
            for (int tn = 0; tn < 4; ++tn)
#pragma unroll
                for (int r = 0; r < 4; ++r) {
                    int row = m0 + wr * 64 + tm * 16 + (lane >> 4) * 4 + r;
                    int col = n0 + wc * 64 + tn * 16 + (lane & 15);
                    float v = acc[tm][tn][r];
                    if (proj == 0) v = v > 0.f ? v + 1.f : __expf(v);
                    C[(long)row * 1024 + col] = v;
                }
    }
}

// ---------------------------------------------------------------------------
// setfeat v7: k folded into MFMA A-operand. Per (b,h) pair, per d:
//   acc += mfma(bf16(k[s,d]*v[s,e]), WKh+WKl / WVh+WVl)
// k scalars prefetched (1 d ahead) from kTg[pair][d][s]; W double-buffered via
// gl16 with counted vmcnt(6). LDS 64KB -> 2 blocks/CU (4 waves/SIMD).
// ---------------------------------------------------------------------------
__global__ __launch_bounds__(512, 4) void setfeat_kernel(
    const float* __restrict__ kTg, const float* __restrict__ vbuf,
    const bf16* __restrict__ Wm4,
    const float* __restrict__ bkmap, const float* __restrict__ bvmap,
    float* __restrict__ Ktail, float* __restrict__ Vtail,
    float* __restrict__ KsetT, float* __restrict__ Vset)
{
    __shared__ char smem[65536];
    bf16* W0 = reinterpret_cast<bf16*>(smem);            // 32KB
    bf16* W1 = reinterpret_cast<bf16*>(smem + 32768);    // 32KB
    const int tid = threadIdx.x;
    const int grp = tid >> 8, tl = tid & 255;
    const int lane = tl & 63, wid = tl >> 6;
    const int wr = wid >> 1, wc = wid & 1;
    const int pairIdx = blockIdx.x * 2 + grp;
    const int b = pairIdx >> 4, h = pairIdx & 15;
    const long base_kv = ((long)b * 64) * C_DIM + h * HS;
    const float* kp = kTg + (long)pairIdx * 4096;        // [d][s]

    // v fragments fp32 in registers (rows wr*32 + tm*16 + (lane&15))
    float vv0[2][8], vv1[2][8];
#pragma unroll
    for (int kk = 0; kk < 2; ++kk) {
        const float* p0 = &vbuf[base_kv +
            (long)(wr * 32 + (lane & 15)) * C_DIM + kk * 32 + (lane >> 4) * 8];
        const float* p1 = &vbuf[base_kv +
            (long)(wr * 32 + 16 + (lane & 15)) * C_DIM + kk * 32 + (lane >> 4) * 8];
        *reinterpret_cast<float4*>(&vv0[kk][0]) = reinterpret_cast<const float4*>(p0)[0];
        *reinterpret_cast<float4*>(&vv0[kk][4]) = reinterpret_cast<const float4*>(p0)[1];
        *reinterpret_cast<float4*>(&vv1[kk][0]) = reinterpret_cast<const float4*>(p1)[0];
        *reinterpret_cast<float4*>(&vv1[kk][4]) = reinterpret_cast<const float4*>(p1)[1];
    }
    // prologue: k scalars for d=0, stage W(0)
    float ks0 = kp[wr * 32 + (lane & 15)];
    float ks1 = kp[wr * 32 + 16 + (lane & 15)];
#pragma unroll
    for (int i = 0; i < 4; ++i) {
        int cc = tid + i * 512;
        gl16(&Wm4[(long)cc * 8], smem + (long)cc * 16);
    }
    f32x4 accK[2][2] = {}, accV[2][2] = {};

    for (int d = 0; d < 64; ++d) {
        bf16* Wcur = (d & 1) ? W1 : W0;
        char* Wnxt = (d & 1) ? smem : smem + 32768;
        __builtin_amdgcn_s_barrier();   // all waves done compute(d-1); buffer safe
        float kn0 = 0.f, kn1 = 0.f;
        if (d < 63) {
            kn0 = kp[(d + 1) * 64 + wr * 32 + (lane & 15)];
            kn1 = kp[(d + 1) * 64 + wr * 32 + 16 + (lane & 15)];
#pragma unroll
            for (int i = 0; i < 4; ++i) {
                int cc = tid + i * 512;
                gl16(&Wm4[(long)(d + 1) * 16384 + (long)cc * 8], Wnxt + (long)cc * 16);
            }
            asm volatile("s_waitcnt vmcnt(6)" ::: "memory");  // stage(d)+kload(d) landed
        } else {
            asm volatile("s_waitcnt vmcnt(0)" ::: "memory");
        }
#pragma unroll
        for (int kk = 0; kk < 2; ++kk) {
            short8 bkh[2], bkl[2], bvh[2], bvl[2];
#pragma unroll
            for (int t = 0; t < 2; ++t) {
                int rb = wc * 32 + t * 16 + (lane & 15);
                int ch = kk * 4 + (lane >> 4);
                bkh[t] = *tchunk(Wcur,         rb, ch);
                bkl[t] = *tchunk(Wcur + 4096,  rb, ch);
                bvh[t] = *tchunk(Wcur + 8192,  rb, ch);
                bvl[t] = *tchunk(Wcur + 12288, rb, ch);
            }
            short8 a0, a1;
#pragma unroll
            for (int j = 0; j < 8; ++j) {
                a0[j] = bfbits(ks0 * vv0[kk][j]);
                a1[j] = bfbits(ks1 * vv1[kk][j]);
            }
#pragma unroll
            for (int tn = 0; tn < 2; ++tn) {
                accK[0][tn] = __builtin_amdgcn_mfma_f32_16x16x32_bf16(a0, bkh[tn], accK[0][tn], 0, 0, 0);
                accK[0][tn] = __builtin_amdgcn_mfma_f32_16x16x32_bf16(a0, bkl[tn], accK[0][tn], 0, 0, 0);
                accK[1][tn] = __builtin_amdgcn_mfma_f32_16x16x32_bf16(a1, bkh[tn], accK[1][tn], 0, 0, 0);
                accK[1][tn] = __builtin_amdgcn_mfma_f32_16x16x32_bf16(a1, bkl[tn], accK[1][tn], 0, 0, 0);
                accV[0][tn] = __builtin_amdgcn_mfma_f32_16x16x32_bf16(a0, bvh[tn], accV[0][tn], 0, 0, 0);
                accV[0][tn] = __builtin_amdgcn_mfma_f32_16x16x32_bf16(a0, bvl[tn], accV[0][tn], 0, 0, 0);
                accV[1][tn] = __builtin_amdgcn_mfma_f32_16x16x32_bf16(a1, bvh[tn], accV[1][tn], 0, 0, 0);
                accV[1][tn] = __builtin_amdgcn_mfma_f32_16x16x32_bf16(a1, bvl[tn], accV[1][tn], 0, 0, 0);
            }
        }
        ks0 = kn0; ks1 = kn1;
    }
    __syncthreads();   // all waves done reading W bufs before overlay writes
    // per-pair Wall overlays: pair0 [0,32KB), pair1 [32KB,64KB)
    float(*WallK)[64] = reinterpret_cast<float(*)[64]>(smem + grp * 32768);
    float(*WallV)[64] = reinterpret_cast<float(*)[64]>(smem + grp * 32768 + 16384);
#pragma unroll
    for (int tm = 0; tm < 2; ++tm)
#pragma unroll
        for (int tn = 0; tn < 2; ++tn)
#pragma unroll
            for (int r = 0; r < 4; ++r) {
                int row = wr * 32 + tm * 16 + (lane >> 4) * 4 + r;
                int col = wc * 32 + tn * 16 + (lane & 15);
                WallK[row][col] = (tm == 0 ? accK[0][tn][r] : accK[1][tn][r]);
                WallV[row][col] = (tm == 0 ? accV[0][tn][r] : accV[1][tn][r]);
            }
    __syncthreads();
    if (tl < 128) {
        int i = tl & 63;
        bool isV = tl >= 64;
        const float bi = isV ? bvmap[i] : bkmap[i];
        float run = 0.f;
        for (int s = 0; s < 64; ++s) {
            run += isV ? WallV[s][i] : WallK[s][i];
            float val = run + bi;
            long t = (long)b * 64 + s;
            if (isV) Vtail[t * C_DIM + h * HS + i] = val;
            else     Ktail[t * C_DIM + h * HS + i] = val;
            if (s == 63) {
                if (isV) Vset[(b * NHEAD + h) * HS + i] = val;
                else     KsetT[h * 2048 + i * 32 + b] = val;  // transposed [h][d][b]
            }
        }
    }
}

// ---------------------------------------------------------------------------
// Attention: one wave per (t,h). Tail logit wave-parallel; set-dot reads
// KsetT[h][d][s] (lane s consecutive -> coalesced). Writes pre-swizzled hi/lo.
// ---------------------------------------------------------------------------
__global__ __launch_bounds__(256) void attn_kernel(
    const float* __restrict__ qbuf, const float* __restrict__ KsetT,
    const float* __restrict__ Vset, const float* __restrict__ Ktail,
    const float* __restrict__ Vtail, bf16* __restrict__ atth, bf16* __restrict__ attl)
{
    __shared__ float qsh[4][64];
    __shared__ float attsh[4][64];
    const int tid = threadIdx.x, lane = tid & 63, wid = tid >> 6;
    const int g = blockIdx.x * 4 + wid;
    const int t = g >> 4, h = g & 15;
    const int nb = t >> 6;
    const float scale = 0.125f;
    const long qoff = (long)t * C_DIM + h * HS;
    float qv = qbuf[qoff + lane];
    qsh[wid][lane] = qv;
    // tail logit: wave-parallel dot + reduce (all lanes get sum)
    float tp = qv * Ktail[qoff + lane];
    for (int off = 32; off; off >>= 1) tp += __shfl_xor(tp, off, 64);
    __syncthreads();
    float logit = -INFINITY;
    if (lane < nb) {
        float s = 0.f;
        const float* Kp = &KsetT[h * 2048 + lane];     // + d*32
        for (int d = 0; d < 64; ++d) s += qsh[wid][d] * Kp[d * 32];
        logit = s * scale;
    } else if (lane == nb) {
        logit = tp * scale;
    }
    float m = logit;
    for (int off = 32; off; off >>= 1) m = fmaxf(m, __shfl_xor(m, off, 64));
    float e = (lane <= nb) ? __expf(logit - m) : 0.f;
    float sum = e;
    for (int off = 32; off; off >>= 1) sum += __shfl_xor(sum, off, 64);
    attsh[wid][lane] = e / sum;
    __syncthreads();
    float out = 0.f;
    for (int s = 0; s < nb; ++s)
        out += attsh[wid][s] * Vset[(s * NHEAD + h) * HS + lane];
    out += attsh[wid][nb] * Vtail[qoff + lane];
    bf16 hb = __float2bfloat16(out);
    int csw = (((lane >> 3) ^ (t & 7)) << 3) | (lane & 7);
    long po = (long)t * 1024 + h * 64 + csw;
    atth[po] = hb;
    attl[po] = __float2bfloat16(out - bf2f(hb));
}

// ---------------------------------------------------------------------------
// Final GEMM: out = attout @ Wc^T + bc. 128x64 tiles, global_load_lds staging.
// ---------------------------------------------------------------------------
__global__ __launch_bounds__(256) void gemm_final_kernel(
    const bf16* __restrict__ ah, const bf16* __restrict__ al,
    const bf16* __restrict__ bh, const bf16* __restrict__ bl,
    const float* __restrict__ bias, float* __restrict__ C)
{
    __shared__ bf16 lds[24576];   // Ah 0 | Al 8192 | Bh 16384 | Bl 20480 (elems)
    const int tid = threadIdx.x;
    const int lane = tid & 63, wid = tid >> 6;
    const int wr = wid >> 1, wc = wid & 1;
    const int m0 = blockIdx.y * 128, n0 = blockIdx.x * 64;
    char* lb = reinterpret_cast<char*>(lds);

    f32x4 acc[4][2] = {};
    for (int kt = 0; kt < 16; ++kt) {
        const int k0 = kt << 6;
#pragma unroll
        for (int i = 0; i < 4; ++i) {
            int cc = tid + i * 256;
            int row = cc >> 3, j = cc & 7;
            long so = (long)(m0 + row) * 1024 + k0 + j * 8;
            gl16(&ah[so], lb + cc * 16);
            gl16(&al[so], lb + 16384 + cc * 16);
        }
#pragma unroll
        for (int i = 0; i < 2; ++i) {
            int cc = tid + i * 256;
            int row = cc >> 3, j = cc & 7;
            long so = (long)(n0 + row) * 1024 + k0 + j * 8;
            gl16(&bh[so], lb + 32768 + cc * 16);
            gl16(&bl[so], lb + 40960 + cc * 16);
        }
        __syncthreads();
#pragma unroll
        for (int kk = 0; kk < 2; ++kk) {
            short8 afh[4], afl[4], bfh[2], bfl[2];
#pragma unroll
            for (int t = 0; t < 4; ++t) {
                int ra = wr * 64 + t * 16 + (lane & 15);
                int ch = kk * 4 + (lane >> 4);
                afh[t] = *tchunk(lds, ra, ch);
                afl[t] = *tchunk(lds + 8192, ra, ch);
            }
#pragma unroll
            for (int t = 0; t < 2; ++t) {
                int rb = wc * 32 + t * 16 + (lane & 15);
                int ch = kk * 4 + (lane >> 4);
                bfh[t] = *tchunk(lds + 16384, rb, ch);
                bfl[t] = *tchunk(lds + 20480, rb, ch);
            }
#pragma unroll
            for (int tm = 0; tm < 4; ++tm)
#pragma unroll
                for (int tn = 0; tn < 2; ++tn) {
                    acc[tm][tn] = __builtin_amdgcn_mfma_f32_16x16x32_bf16(
                        afh[tm], bfh[tn], acc[tm][tn], 0, 0, 0);
                    acc[tm][tn] = __builtin_amdgcn_mfma_f32_16x16x32_bf16(
                        afh[tm], bfl[tn], acc[tm][tn], 0, 0, 0);
                    acc[tm][tn] = __builtin_amdgcn_mfma_f32_16x16x32_bf16(
                        afl[tm], bfh[tn], acc[tm][tn], 0, 0, 0);
                }
        }
        __syncthreads();
    }
#pragma unroll
    for (int tm = 0; tm < 4; ++tm)
#pragma unroll
        for (int tn = 0; tn < 2; ++tn)
#pragma unroll
            for (int r = 0; r < 4; ++r) {
                int row = m0 + wr * 64 + tm * 16 + (lane >> 4) * 4 + r;
                int col = n0 + wc * 32 + tn * 16 + (lane & 15);
                C[(long)row * 1024 + col] = acc[tm][tn][r] + bias[col];
            }
}

// ---------------------------------------------------------------------------
extern "C" void kernel_launch(void* const* d_in, const int* in_sizes, int n_in,
                              void* d_out, int out_size, void* d_ws, size_t ws_size,
                              hipStream_t stream)
{
    const float* x     = (const float*)d_in[0];
    const float* Wq    = (const float*)d_in[1];
    const float* Wk    = (const float*)d_in[2];
    const float* Wv    = (const float*)d_in[3];
    const float* Wkmap = (const float*)d_in[4];
    const float* bkmap = (const float*)d_in[5];
    const float* Wvmap = (const float*)d_in[6];
    const float* bvmap = (const float*)d_in[7];
    const float* Wc    = (const float*)d_in[8];
    const float* bc    = (const float*)d_in[9];
    float* out = (float*)d_out;

    char* ws = (char*)d_ws;
    const long MB = 1l << 20;
    float* q   = (float*)(ws + 0 * MB);        // 8MB
    float* kTg = (float*)(ws + 8 * MB);        // 8MB [pair][d][s] (dead after setfeat)
    float* v   = (float*)(ws + 16 * MB);       // 8MB
    bf16* xh   = (bf16*)(ws + 24 * MB);        // 4MB (dead after qkv)
    bf16* xl   = (bf16*)(ws + 28 * MB);        // 4MB
    bf16* wqh  = (bf16*)(ws + 32 * MB);        // 2MB each (dead after qkv)
    bf16* wql  = (bf16*)(ws + 34 * MB);
    bf16* wkh  = (bf16*)(ws + 36 * MB);
    bf16* wkl  = (bf16*)(ws + 38 * MB);
    bf16* wvh  = (bf16*)(ws + 40 * MB);
    bf16* wvl  = (bf16*)(ws + 42 * MB);
    bf16* Wm4  = (bf16*)(ws + 44 * MB);        // 2MB (dead after setfeat)
    // post-qkv overlays:
    float* Ktail = (float*)(ws + 24 * MB);     // 8MB over xh/xl
    float* Vtail = (float*)(ws + 32 * MB);     // 8MB over wq/wk
    float* KsetT = (float*)(ws + 40 * MB);     // 128KB over wvh
    float* Vset  = (float*)(ws + 41 * MB);     // 128KB
    bf16* atth   = (bf16*)(ws + 8 * MB);       // 4MB over kTg (dead after setfeat)
    bf16* attl   = (bf16*)(ws + 12 * MB);      // 4MB
    bf16* wch    = (bf16*)(ws + 44 * MB);      // 2MB over Wm4 (written after setfeat)
    bf16* wcl    = (bf16*)(ws + 46 * MB);      // 2MB

    presplit_all_kernel<<<2560, 256, 0, stream>>>(x, Wq, Wk, Wv, xh, xl,
                                                  wqh, wql, wkh, wkl, wvh, wvl);
    presplit_wmap_kernel<<<64, 256, 0, stream>>>(Wkmap, Wvmap, Wm4);
    qkv_kernel<<<dim3(24, 16), 256, 0, stream>>>(xh, xl, wqh, wql, wkh, wkl,
                                                 wvh, wvl, q, kTg);
    setfeat_kernel<<<256, 512, 0, stream>>>(kTg, v, Wm4, bkmap, bvmap,
                                            Ktail, Vtail, KsetT, Vset);
    presplit_wc_kernel<<<512, 256, 0, stream>>>(Wc, wch, wcl);
    attn_kernel<<<8192, 256, 0, stream>>>(q, KsetT, Vset, Ktail, Vtail, atth, attl);
    gemm_final_kernel<<<dim3(16, 16), 256, 0, stream>>>(atth, attl, wch, wcl, bc, out);
}

// Round 11
// 253.338 us; speedup vs baseline: 1.0212x; 1.0212x over previous
//
#include <hip/hip_runtime.h>
#include <hip/hip_bf16.h>
#include <math.h>

typedef __hip_bfloat16 bf16;
typedef __attribute__((ext_vector_type(8))) short short8;
typedef __attribute__((ext_vector_type(4))) float f32x4;

#define C_DIM 1024
#define NHEAD 16
#define HS 64

__device__ __forceinline__ float bf2f(bf16 x) { return __bfloat162float(x); }
__device__ __forceinline__ short bfbits(float x) {
    bf16 h = __float2bfloat16(x);
    return *reinterpret_cast<short*>(&h);
}

// Async global->LDS, 16B per lane. LDS dest is wave-uniform base + lane*16.
__device__ __forceinline__ void gl16(const void* g, void* l) {
    __builtin_amdgcn_global_load_lds(
        (const __attribute__((address_space(1))) unsigned int*)g,
        (__attribute__((address_space(3))) unsigned int*)l, 16, 0, 0);
}

// Split 8 consecutive floats into bf16 hi + bf16 lo (residual) short8s.
__device__ __forceinline__ void split8(const float* p, short8& h, short8& l) {
    float4 f0 = reinterpret_cast<const float4*>(p)[0];
    float4 f1 = reinterpret_cast<const float4*>(p)[1];
    float vals[8] = {f0.x, f0.y, f0.z, f0.w, f1.x, f1.y, f1.z, f1.w};
#pragma unroll
    for (int j = 0; j < 8; ++j) {
        bf16 hb = __float2bfloat16(vals[j]);
        float r = vals[j] - __bfloat162float(hb);
        h[j] = *reinterpret_cast<short*>(&hb);
        bf16 lb = __float2bfloat16(r);
        l[j] = *reinterpret_cast<short*>(&lb);
    }
}

// Swizzled-LDS fragment read: [rows][64] bf16 tile, 16B chunk slot = ch ^ (row&7).
__device__ __forceinline__ short8* tchunk(bf16* tile, int row, int ch) {
    return reinterpret_cast<short8*>(tile + row * 64 + (((ch) ^ (row & 7)) << 3));
}

// ---------------------------------------------------------------------------
// Pre-split x,Wq,Wk,Wv -> bf16 hi/lo, stored PRE-SWIZZLED (chunk bits [5:3] of
// the element index XOR'd with row&7, row = idx>>10). Grid 2560 x 256.
// ---------------------------------------------------------------------------
__global__ __launch_bounds__(256) void presplit_all_kernel(
    const float* __restrict__ x, const float* __restrict__ Wq,
    const float* __restrict__ Wk, const float* __restrict__ Wv,
    bf16* __restrict__ xh, bf16* __restrict__ xl,
    bf16* __restrict__ wqh, bf16* __restrict__ wql,
    bf16* __restrict__ wkh, bf16* __restrict__ wkl,
    bf16* __restrict__ wvh, bf16* __restrict__ wvl)
{
    int blk = blockIdx.x;
    const float* src; bf16 *dh, *dl; long off;
    if (blk < 1024)      { src = x;  dh = xh;  dl = xl;  off = (long)blk * 2048; }
    else if (blk < 1536) { src = Wq; dh = wqh; dl = wql; off = (long)(blk - 1024) * 2048; }
    else if (blk < 2048) { src = Wk; dh = wkh; dl = wkl; off = (long)(blk - 1536) * 2048; }
    else                 { src = Wv; dh = wvh; dl = wvl; off = (long)(blk - 2048) * 2048; }
    long p = off + threadIdx.x * 8;
    int j = (int)(((p >> 3) ^ (p >> 10)) & 7);
    long dp = (p & ~56l) | ((long)j << 3);
    short8 h8, l8;
    split8(&src[p], h8, l8);
    *reinterpret_cast<short8*>(&dh[dp]) = h8;
    *reinterpret_cast<short8*>(&dl[dp]) = l8;
}

// Pre-split Wc (pre-swizzled). Runs after setfeat (dest overlays Wm4).
__global__ __launch_bounds__(256) void presplit_wc_kernel(
    const float* __restrict__ Wc, bf16* __restrict__ wch, bf16* __restrict__ wcl)
{
    long p = (long)blockIdx.x * 2048 + threadIdx.x * 8;
    int j = (int)(((p >> 3) ^ (p >> 10)) & 7);
    long dp = (p & ~56l) | ((long)j << 3);
    short8 h8, l8;
    split8(&Wc[p], h8, l8);
    *reinterpret_cast<short8*>(&wch[dp]) = h8;
    *reinterpret_cast<short8*>(&wcl[dp]) = l8;
}

// ---------------------------------------------------------------------------
// Pre-split Wkmap/Wvmap -> Wm4[d][part][row][e] bf16 (part 0=Kh 1=Kl 2=Vh 3=Vl),
// pre-swizzled within each 64-elem row. Grid 64 (one block per d).
// ---------------------------------------------------------------------------
__global__ __launch_bounds__(256) void presplit_wmap_kernel(
    const float* __restrict__ WK, const float* __restrict__ WV, bf16* __restrict__ Wm4)
{
    int d = blockIdx.x;
    int row = threadIdx.x >> 2, e0 = (threadIdx.x & 3) * 16;
    int sw0 = (((e0 >> 3) + 0) ^ (row & 7)) & 7;
    int sw1 = (((e0 >> 3) + 1) ^ (row & 7)) & 7;
    const float* pk = &WK[(long)row * 4096 + d * 64 + e0];
    const float* pv = &WV[(long)row * 4096 + d * 64 + e0];
    long bKh = ((long)(d * 4 + 0) * 64 + row) * 64;
    long bKl = ((long)(d * 4 + 1) * 64 + row) * 64;
    long bVh = ((long)(d * 4 + 2) * 64 + row) * 64;
    long bVl = ((long)(d * 4 + 3) * 64 + row) * 64;
    short8 h8, l8;
    split8(pk, h8, l8);     *(short8*)&Wm4[bKh + sw0*8] = h8; *(short8*)&Wm4[bKl + sw0*8] = l8;
    split8(pk + 8, h8, l8); *(short8*)&Wm4[bKh + sw1*8] = h8; *(short8*)&Wm4[bKl + sw1*8] = l8;
    split8(pv, h8, l8);     *(short8*)&Wm4[bVh + sw0*8] = h8; *(short8*)&Wm4[bVl + sw0*8] = l8;
    split8(pv + 8, h8, l8); *(short8*)&Wm4[bVh + sw1*8] = h8; *(short8*)&Wm4[bVl + sw1*8] = l8;
}

// ---------------------------------------------------------------------------
// Fused QKV GEMM; staging via global_load_lds from pre-swizzled operands.
// proj==1 (k): epilogue transposes per-wave 64x64 quadrant via LDS and writes
// kTg[pair][d][s] (pair = tblk*16 + h) instead of the normal k layout.
// ---------------------------------------------------------------------------
__global__ __launch_bounds__(256) void qkv_kernel(
    const bf16* __restrict__ xh, const bf16* __restrict__ xl,
    const bf16* __restrict__ wqh, const bf16* __restrict__ wql,
    const bf16* __restrict__ wkh, const bf16* __restrict__ wkl,
    const bf16* __restrict__ wvh, const bf16* __restrict__ wvl,
    float* __restrict__ qkv, float* __restrict__ kTg)
{
    __shared__ bf16 lds[32768];   // Ah 0 | Al 8192 | Bh 16384 | Bl 24576 (elems)
    const int tid = threadIdx.x;
    const int lane = tid & 63, wid = tid >> 6;
    const int wr = wid >> 1, wc = wid & 1;
    const int proj = blockIdx.x >> 3;
    const int n0 = (blockIdx.x & 7) * 128;
    const int m0 = blockIdx.y * 128;
    const bf16* Bhp = proj == 0 ? wqh : (proj == 1 ? wkh : wvh);
    const bf16* Blp = proj == 0 ? wql : (proj == 1 ? wkl : wvl);
    float* C = qkv + (long)proj * 2097152;
    char* lb = reinterpret_cast<char*>(lds);

    f32x4 acc[4][4] = {};
    for (int kt = 0; kt < 16; ++kt) {
        const int k0 = kt << 6;
#pragma unroll
        for (int i = 0; i < 4; ++i) {
            int cc = tid + i * 256;             // 1024 chunks per tile
            int row = cc >> 3, j = cc & 7;
            long soA = (long)(m0 + row) * 1024 + k0 + j * 8;
            long soB = (long)(n0 + row) * 1024 + k0 + j * 8;
            gl16(&xh[soA],  lb + cc * 16);
            gl16(&xl[soA],  lb + 16384 + cc * 16);
            gl16(&Bhp[soB], lb + 32768 + cc * 16);
            gl16(&Blp[soB], lb + 49152 + cc * 16);
        }
        __syncthreads();
#pragma unroll
        for (int kk = 0; kk < 2; ++kk) {
            short8 afh[4], afl[4], bfh[4], bfl[4];
#pragma unroll
            for (int t = 0; t < 4; ++t) {
                int ra = wr * 64 + t * 16 + (lane & 15);
                int rb = wc * 64 + t * 16 + (lane & 15);
                int ch = kk * 4 + (lane >> 4);
                afh[t] = *tchunk(lds, ra, ch);
                afl[t] = *tchunk(lds + 8192, ra, ch);
                bfh[t] = *tchunk(lds + 16384, rb, ch);
                bfl[t] = *tchunk(lds + 24576, rb, ch);
            }
#pragma unroll
            for (int tm = 0; tm < 4; ++tm)
#pragma unroll
                for (int tn = 0; tn < 4; ++tn) {
                    acc[tm][tn] = __builtin_amdgcn_mfma_f32_16x16x32_bf16(
                        afh[tm], bfh[tn], acc[tm][tn], 0, 0, 0);
                    acc[tm][tn] = __builtin_amdgcn_mfma_f32_16x16x32_bf16(
                        afh[tm], bfl[tn], acc[tm][tn], 0, 0, 0);
                    acc[tm][tn] = __builtin_amdgcn_mfma_f32_16x16x32_bf16(
                        afl[tm], bfh[tn], acc[tm][tn], 0, 0, 0);
                }
        }
        __syncthreads();
    }
    if (proj == 1) {
        // per-wave 64x64 transpose via its own 16KB LDS quarter (XOR-swizzled)
        float* lf = reinterpret_cast<float*>(lds) + wid * 4096;
#pragma unroll
        for (int tm = 0; tm < 4; ++tm)
#pragma unroll
            for (int tn = 0; tn < 4; ++tn)
#pragma unroll
                for (int r = 0; r < 4; ++r) {
                    int s = tm * 16 + (lane >> 4) * 4 + r;
                    int dd = tn * 16 + (lane & 15);
                    float v = acc[tm][tn][r];
                    v = v > 0.f ? v + 1.f : __expf(v);
                    lf[dd * 64 + (s ^ dd)] = v;
                }
        asm volatile("s_waitcnt lgkmcnt(0)" ::: "memory");
        __builtin_amdgcn_sched_barrier(0);
        int pair = (blockIdx.y * 2 + wr) * 16 + ((blockIdx.x & 7) * 2 + wc);
        long pb = (long)pair * 4096;
        int s0 = (lane & 15) * 4;
#pragma unroll
        for (int ii = 0; ii < 16; ++ii) {
            int dd = (lane >> 4) * 16 + ii;
            float4 o;
            o.x = lf[dd * 64 + ((s0 + 0) ^ dd)];
            o.y = lf[dd * 64 + ((s0 + 1) ^ dd)];
            o.z = lf[dd * 64 + ((s0 + 2) ^ dd)];
            o.w = lf[dd * 64 + ((s0 + 3) ^ dd)];
            *reinterpret_cast<float4*>(&kTg[pb + (long)dd * 64 + s0]) = o;
        }
    } else {
#pragma unroll
        for (int tm = 0; tm < 4; ++tm)
#pragma unroll
            for (int tn = 0; tn < 4; ++tn)
#pragma unroll
                for (int r = 0; r < 4; ++r) {
                    int row = m0 + wr * 64 + tm * 16 + (lane >> 4) * 4 + r;
                    int col = n0 + wc * 64 + tn * 16 + (lane & 15);
                    float v = acc[tm][tn][r];
                    if (proj == 0) v = v > 0.f ? v + 1.f : __expf(v);
                    C[(long)row * 1024 + col] = v;
                }
    }
}

// ---------------------------------------------------------------------------
// setfeat v8: K/V side-split blocks for real occupancy. Grid 512 x 512thr:
// side = bx&1 (0=K,1=V), 2 pairs/block share one side's W staging.
// LDS = 2x16KB W dbuf (hi+lo of one side) = 32KB -> 2+ blocks/CU.
// Per d: G = v @ Wside (2-pass MFMA, v-frags in regs); acc += kv[d] * G
// (fp32, post-MFMA); kv broadcast-loaded from kTg, prefetched 1 ahead.
// Counted vmcnt(4) = prev iter's {2 gl16 + 2 kv loads}; one barrier/iter.
// ---------------------------------------------------------------------------
__global__ __launch_bounds__(512, 4) void setfeat_kernel(
    const float* __restrict__ kTg, const float* __restrict__ vbuf,
    const bf16* __restrict__ Wm4,
    const float* __restrict__ bkmap, const float* __restrict__ bvmap,
    float* __restrict__ Ktail, float* __restrict__ Vtail,
    float* __restrict__ KsetT, float* __restrict__ Vset)
{
    __shared__ char smem[32768];
    bf16* W0 = reinterpret_cast<bf16*>(smem);            // 16KB: [hi 8KB][lo 8KB]
    bf16* W1 = reinterpret_cast<bf16*>(smem + 16384);    // 16KB
    const int tid = threadIdx.x;
    const int side = blockIdx.x & 1;                     // 0=K, 1=V
    const int grp = tid >> 8, tl = tid & 255;
    const int lane = tl & 63, wid = tl >> 6;
    const int wr = wid >> 1, wc = wid & 1;
    const int pairIdx = (blockIdx.x >> 1) * 2 + grp;
    const int b = pairIdx >> 4, h = pairIdx & 15;
    const long base_kv = ((long)b * 64) * C_DIM + h * HS;
    const float* kp = kTg + (long)pairIdx * 4096;        // [d][s]
    const long wsideoff = (long)side * 8192;             // elems within d-chunk

    // v fragments (loop-invariant A operand), bf16 in registers
    short8 vh[2][2];
#pragma unroll
    for (int tm = 0; tm < 2; ++tm)
#pragma unroll
        for (int kk = 0; kk < 2; ++kk) {
            const float* vp = &vbuf[base_kv +
                (long)(wr * 32 + tm * 16 + (lane & 15)) * C_DIM + kk * 32 + (lane >> 4) * 8];
            float4 f0 = reinterpret_cast<const float4*>(vp)[0];
            float4 f1 = reinterpret_cast<const float4*>(vp)[1];
            float vals[8] = {f0.x, f0.y, f0.z, f0.w, f1.x, f1.y, f1.z, f1.w};
#pragma unroll
            for (int j = 0; j < 8; ++j) vh[tm][kk][j] = bfbits(vals[j]);
        }
    // prologue: kv(0) + stage(0)
    f32x4 kvc[2];
#pragma unroll
    for (int tm = 0; tm < 2; ++tm)
        kvc[tm] = *reinterpret_cast<const f32x4*>(
            &kp[wr * 32 + tm * 16 + (lane >> 4) * 4]);
#pragma unroll
    for (int i = 0; i < 2; ++i) {
        int cc = tid + i * 512;       // 1024 chunks of 16B
        gl16(&Wm4[wsideoff + (long)cc * 8], smem + (long)cc * 16);
    }
    f32x4 acc[2][2] = {};
    __syncthreads();   // full drain: stage(0)+kv(0) complete

    for (int d = 0; d < 64; ++d) {
        bf16* Wcur = (d & 1) ? W1 : W0;
        char* Wnxt = (d & 1) ? smem : smem + 16384;
        __builtin_amdgcn_s_barrier();   // all waves done compute(d-1); buffer safe
        f32x4 kvn[2] = {};
        if (d < 63) {
#pragma unroll
            for (int i = 0; i < 2; ++i) {
                int cc = tid + i * 512;
                gl16(&Wm4[(long)(d + 1) * 16384 + wsideoff + (long)cc * 8],
                     Wnxt + (long)cc * 16);
            }
#pragma unroll
            for (int tm = 0; tm < 2; ++tm)
                kvn[tm] = *reinterpret_cast<const f32x4*>(
                    &kp[(d + 1) * 64 + wr * 32 + tm * 16 + (lane >> 4) * 4]);
            asm volatile("s_waitcnt vmcnt(4)" ::: "memory");  // iter d's 4 ops landed
        } else {
            asm volatile("s_waitcnt vmcnt(0)" ::: "memory");
        }
        f32x4 G[2][2] = {};
#pragma unroll
        for (int kk = 0; kk < 2; ++kk) {
            short8 bh_[2], bl_[2];
#pragma unroll
            for (int t = 0; t < 2; ++t) {
                int rb = wc * 32 + t * 16 + (lane & 15);
                int ch = kk * 4 + (lane >> 4);
                bh_[t] = *tchunk(Wcur,        rb, ch);
                bl_[t] = *tchunk(Wcur + 4096, rb, ch);
            }
#pragma unroll
            for (int tm = 0; tm < 2; ++tm)
#pragma unroll
                for (int tn = 0; tn < 2; ++tn) {
                    G[tm][tn] = __builtin_amdgcn_mfma_f32_16x16x32_bf16(
                        vh[tm][kk], bh_[tn], G[tm][tn], 0, 0, 0);
                    G[tm][tn] = __builtin_amdgcn_mfma_f32_16x16x32_bf16(
                        vh[tm][kk], bl_[tn], G[tm][tn], 0, 0, 0);
                }
        }
#pragma unroll
        for (int tm = 0; tm < 2; ++tm)
#pragma unroll
            for (int tn = 0; tn < 2; ++tn)
#pragma unroll
                for (int r = 0; r < 4; ++r)
                    acc[tm][tn][r] += kvc[tm][r] * G[tm][tn][r];
        kvc[0] = kvn[0]; kvc[1] = kvn[1];
    }
    __syncthreads();   // all waves done reading W bufs before overlay writes
    // per-pair Wall overlay: grp0 [0,16KB), grp1 [16KB,32KB)
    float(*Wall)[64] = reinterpret_cast<float(*)[64]>(smem + grp * 16384);
#pragma unroll
    for (int tm = 0; tm < 2; ++tm)
#pragma unroll
        for (int tn = 0; tn < 2; ++tn)
#pragma unroll
            for (int r = 0; r < 4; ++r) {
                int row = wr * 32 + tm * 16 + (lane >> 4) * 4 + r;
                int col = wc * 32 + tn * 16 + (lane & 15);
                Wall[row][col] = acc[tm][tn][r];
            }
    __syncthreads();
    if (tl < 64) {
        int i = tl;
        const float bi = side ? bvmap[i] : bkmap[i];
        float run = 0.f;
        for (int s = 0; s < 64; ++s) {
            run += Wall[s][i];
            float val = run + bi;
            long t = (long)b * 64 + s;
            if (side) Vtail[t * C_DIM + h * HS + i] = val;
            else      Ktail[t * C_DIM + h * HS + i] = val;
            if (s == 63) {
                if (side) Vset[(b * NHEAD + h) * HS + i] = val;
                else      KsetT[h * 2048 + i * 32 + b] = val;  // transposed [h][d][b]
            }
        }
    }
}

// ---------------------------------------------------------------------------
// Attention: one wave per (t,h). Tail logit wave-parallel; set-dot reads
// KsetT[h][d][s] (lane s consecutive -> coalesced). Writes pre-swizzled hi/lo.
// ---------------------------------------------------------------------------
__global__ __launch_bounds__(256) void attn_kernel(
    const float* __restrict__ qbuf, const float* __restrict__ KsetT,
    const float* __restrict__ Vset, const float* __restrict__ Ktail,
    const float* __restrict__ Vtail, bf16* __restrict__ atth, bf16* __restrict__ attl)
{
    __shared__ float qsh[4][64];
    __shared__ float attsh[4][64];
    const int tid = threadIdx.x, lane = tid & 63, wid = tid >> 6;
    const int g = blockIdx.x * 4 + wid;
    const int t = g >> 4, h = g & 15;
    const int nb = t >> 6;
    const float scale = 0.125f;
    const long qoff = (long)t * C_DIM + h * HS;
    float qv = qbuf[qoff + lane];
    qsh[wid][lane] = qv;
    // tail logit: wave-parallel dot + reduce (all lanes get sum)
    float tp = qv * Ktail[qoff + lane];
    for (int off = 32; off; off >>= 1) tp += __shfl_xor(tp, off, 64);
    __syncthreads();
    float logit = -INFINITY;
    if (lane < nb) {
        float s = 0.f;
        const float* Kp = &KsetT[h * 2048 + lane];     // + d*32
        for (int d = 0; d < 64; ++d) s += qsh[wid][d] * Kp[d * 32];
        logit = s * scale;
    } else if (lane == nb) {
        logit = tp * scale;
    }
    float m = logit;
    for (int off = 32; off; off >>= 1) m = fmaxf(m, __shfl_xor(m, off, 64));
    float e = (lane <= nb) ? __expf(logit - m) : 0.f;
    float sum = e;
    for (int off = 32; off; off >>= 1) sum += __shfl_xor(sum, off, 64);
    attsh[wid][lane] = e / sum;
    __syncthreads();
    float out = 0.f;
    for (int s = 0; s < nb; ++s)
        out += attsh[wid][s] * Vset[(s * NHEAD + h) * HS + lane];
    out += attsh[wid][nb] * Vtail[qoff + lane];
    bf16 hb = __float2bfloat16(out);
    int csw = (((lane >> 3) ^ (t & 7)) << 3) | (lane & 7);
    long po = (long)t * 1024 + h * 64 + csw;
    atth[po] = hb;
    attl[po] = __float2bfloat16(out - bf2f(hb));
}

// ---------------------------------------------------------------------------
// Final GEMM: out = attout @ Wc^T + bc. 128x64 tiles, global_load_lds staging.
// ---------------------------------------------------------------------------
__global__ __launch_bounds__(256) void gemm_final_kernel(
    const bf16* __restrict__ ah, const bf16* __restrict__ al,
    const bf16* __restrict__ bh, const bf16* __restrict__ bl,
    const float* __restrict__ bias, float* __restrict__ C)
{
    __shared__ bf16 lds[24576];   // Ah 0 | Al 8192 | Bh 16384 | Bl 20480 (elems)
    const int tid = threadIdx.x;
    const int lane = tid & 63, wid = tid >> 6;
    const int wr = wid >> 1, wc = wid & 1;
    const int m0 = blockIdx.y * 128, n0 = blockIdx.x * 64;
    char* lb = reinterpret_cast<char*>(lds);

    f32x4 acc[4][2] = {};
    for (int kt = 0; kt < 16; ++kt) {
        const int k0 = kt << 6;
#pragma unroll
        for (int i = 0; i < 4; ++i) {
            int cc = tid + i * 256;
            int row = cc >> 3, j = cc & 7;
            long so = (long)(m0 + row) * 1024 + k0 + j * 8;
            gl16(&ah[so], lb + cc * 16);
            gl16(&al[so], lb + 16384 + cc * 16);
        }
#pragma unroll
        for (int i = 0; i < 2; ++i) {
            int cc = tid + i * 256;
            int row = cc >> 3, j = cc & 7;
            long so = (long)(n0 + row) * 1024 + k0 + j * 8;
            gl16(&bh[so], lb + 32768 + cc * 16);
            gl16(&bl[so], lb + 40960 + cc * 16);
        }
        __syncthreads();
#pragma unroll
        for (int kk = 0; kk < 2; ++kk) {
            short8 afh[4], afl[4], bfh[2], bfl[2];
#pragma unroll
            for (int t = 0; t < 4; ++t) {
                int ra = wr * 64 + t * 16 + (lane & 15);
                int ch = kk * 4 + (lane >> 4);
                afh[t] = *tchunk(lds, ra, ch);
                afl[t] = *tchunk(lds + 8192, ra, ch);
            }
#pragma unroll
            for (int t = 0; t < 2; ++t) {
                int rb = wc * 32 + t * 16 + (lane & 15);
                int ch = kk * 4 + (lane >> 4);
                bfh[t] = *tchunk(lds + 16384, rb, ch);
                bfl[t] = *tchunk(lds + 20480, rb, ch);
            }
#pragma unroll
            for (int tm = 0; tm < 4; ++tm)
#pragma unroll
                for (int tn = 0; tn < 2; ++tn) {
                    acc[tm][tn] = __builtin_amdgcn_mfma_f32_16x16x32_bf16(
                        afh[tm], bfh[tn], acc[tm][tn], 0, 0, 0);
                    acc[tm][tn] = __builtin_amdgcn_mfma_f32_16x16x32_bf16(
                        afh[tm], bfl[tn], acc[tm][tn], 0, 0, 0);
                    acc[tm][tn] = __builtin_amdgcn_mfma_f32_16x16x32_bf16(
                        afl[tm], bfh[tn], acc[tm][tn], 0, 0, 0);
                }
        }
        __syncthreads();
    }
#pragma unroll
    for (int tm = 0; tm < 4; ++tm)
#pragma unroll
        for (int tn = 0; tn < 2; ++tn)
#pragma unroll
            for (int r = 0; r < 4; ++r) {
                int row = m0 + wr * 64 + tm * 16 + (lane >> 4) * 4 + r;
                int col = n0 + wc * 32 + tn * 16 + (lane & 15);
                C[(long)row * 1024 + col] = acc[tm][tn][r] + bias[col];
            }
}

// ---------------------------------------------------------------------------
extern "C" void kernel_launch(void* const* d_in, const int* in_sizes, int n_in,
                              void* d_out, int out_size, void* d_ws, size_t ws_size,
                              hipStream_t stream)
{
    const float* x     = (const float*)d_in[0];
    const float* Wq    = (const float*)d_in[1];
    const float* Wk    = (const float*)d_in[2];
    const float* Wv    = (const float*)d_in[3];
    const float* Wkmap = (const float*)d_in[4];
    const float* bkmap = (const float*)d_in[5];
    const float* Wvmap = (const float*)d_in[6];
    const float* bvmap = (const float*)d_in[7];
    const float* Wc    = (const float*)d_in[8];
    const float* bc    = (const float*)d_in[9];
    float* out = (float*)d_out;

    char* ws = (char*)d_ws;
    const long MB = 1l << 20;
    float* q   = (float*)(ws + 0 * MB);        // 8MB
    float* kTg = (float*)(ws + 8 * MB);        // 8MB [pair][d][s] (dead after setfeat)
    float* v   = (float*)(ws + 16 * MB);       // 8MB
    bf16* xh   = (bf16*)(ws + 24 * MB);        // 4MB (dead after qkv)
    bf16* xl   = (bf16*)(ws + 28 * MB);        // 4MB
    bf16* wqh  = (bf16*)(ws + 32 * MB);        // 2MB each (dead after qkv)
    bf16* wql  = (bf16*)(ws + 34 * MB);
    bf16* wkh  = (bf16*)(ws + 36 * MB);
    bf16* wkl  = (bf16*)(ws + 38 * MB);
    bf16* wvh  = (bf16*)(ws + 40 * MB);
    bf16* wvl  = (bf16*)(ws + 42 * MB);
    bf16* Wm4  = (bf16*)(ws + 44 * MB);        // 2MB (dead after setfeat)
    // post-qkv overlays:
    float* Ktail = (float*)(ws + 24 * MB);     // 8MB over xh/xl
    float* Vtail = (float*)(ws + 32 * MB);     // 8MB over wq/wk
    float* KsetT = (float*)(ws + 40 * MB);     // 128KB over wvh
    float* Vset  = (float*)(ws + 41 * MB);     // 128KB
    bf16* atth   = (bf16*)(ws + 8 * MB);       // 4MB over kTg (dead after setfeat)
    bf16* attl   = (bf16*)(ws + 12 * MB);      // 4MB
    bf16* wch    = (bf16*)(ws + 44 * MB);      // 2MB over Wm4 (written after setfeat)
    bf16* wcl    = (bf16*)(ws + 46 * MB);      // 2MB

    presplit_all_kernel<<<2560, 256, 0, stream>>>(x, Wq, Wk, Wv, xh, xl,
                                                  wqh, wql, wkh, wkl, wvh, wvl);
    presplit_wmap_kernel<<<64, 256, 0, stream>>>(Wkmap, Wvmap, Wm4);
    qkv_kernel<<<dim3(24, 16), 256, 0, stream>>>(xh, xl, wqh, wql, wkh, wkl,
                                                 wvh, wvl, q, kTg);
    setfeat_kernel<<<512, 512, 0, stream>>>(kTg, v, Wm4, bkmap, bvmap,
                                            Ktail, Vtail, KsetT, Vset);
    presplit_wc_kernel<<<512, 256, 0, stream>>>(Wc, wch, wcl);
    attn_kernel<<<8192, 256, 0, stream>>>(q, KsetT, Vset, Ktail, Vtail, atth, attl);
    gemm_final_kernel<<<dim3(16, 16), 256, 0, stream>>>(atth, attl, wch, wcl, bc, out);
}